// Round 1
// baseline (654.615 us; speedup 1.0000x reference)
//
#include <hip/hip_runtime.h>
#include <cfloat>

// Problem constants
#define N_ROWS 32768
#define N_CLS  2048
#define DIM    512

// 128x128 tile, BK=32, 4 waves of 64x64 each, mfma_f32_16x16x32_bf16
#define LDR 40   // padded LDS row stride in bf16 elements (32 + 8 pad)

typedef __attribute__((ext_vector_type(8))) short short8;
typedef __attribute__((ext_vector_type(4))) short short4v;
typedef __attribute__((ext_vector_type(4))) float f32x4;

__device__ __forceinline__ unsigned f2bf_bits(float x) {
    union { float f; unsigned u; } a; a.f = x;
    return (a.u + 0x7fffu + ((a.u >> 16) & 1u)) >> 16;   // RNE, inputs are finite normals
}
__device__ __forceinline__ float bf_to_f(unsigned bits) {
    union { unsigned u; float f; } a; a.u = bits << 16;
    return a.f;
}
__device__ __forceinline__ void split_bf(float x, short &h, short &l) {
    unsigned hb = f2bf_bits(x);
    h = (short)hb;
    float r = x - bf_to_f(hb);          // exact (Sterbenz-ish; hi close to x)
    l = (short)f2bf_bits(r);
}

// ---------------- m2[j] = sum_d muK[j,d]^2 ----------------
__global__ __launch_bounds__(256) void m2_kernel(const float* __restrict__ muK,
                                                 float* __restrict__ m2) {
    const int j = blockIdx.x;
    const int t = threadIdx.x;
    const float* r = muK + (size_t)j * DIM;
    float a = r[t], b = r[t + 256];
    float s = a * a + b * b;
    for (int off = 32; off; off >>= 1) s += __shfl_xor(s, off);
    __shared__ float sw[4];
    if ((t & 63) == 0) sw[t >> 6] = s;
    __syncthreads();
    if (t == 0) m2[j] = sw[0] + sw[1] + sw[2] + sw[3];
}

// ---------------- scores GEMM: S[i,j] = 2*dot(X[i,:],muK[j,:]) - m2[j] ----------------
// bf16x3 split-precision: dot ~= hi*hi + hi*lo + lo*hi (fp32 MFMA accumulate)
__global__ __launch_bounds__(256) void gemm_kernel(const float* __restrict__ X,
                                                   const float* __restrict__ muK,
                                                   const float* __restrict__ m2,
                                                   float* __restrict__ S) {
    __shared__ __align__(16) short Ah[128 * LDR];
    __shared__ __align__(16) short Al[128 * LDR];
    __shared__ __align__(16) short Bh[128 * LDR];
    __shared__ __align__(16) short Bl[128 * LDR];

    const int tid  = threadIdx.x;
    const int n0   = blockIdx.x * 128;   // class tile
    const int m0   = blockIdx.y * 128;   // row tile
    const int w    = tid >> 6;
    const int lane = tid & 63;
    const int wm   = (w >> 1) * 64;      // wave 64x64 subtile
    const int wn   = (w & 1) * 64;
    const int l16  = lane & 15;
    const int quad = lane >> 4;

    f32x4 acc[4][4];
#pragma unroll
    for (int mt = 0; mt < 4; ++mt)
#pragma unroll
        for (int nt = 0; nt < 4; ++nt)
            acc[mt][nt] = (f32x4){0.f, 0.f, 0.f, 0.f};

    for (int kt = 0; kt < DIM; kt += 32) {
        __syncthreads();
        // ---- stage: load fp32, split to (hi,lo) bf16, write LDS ----
#pragma unroll
        for (int i = 0; i < 4; ++i) {
            int idx = tid + 256 * i;          // 0..1023 float4 slots
            int row = idx >> 3;               // 0..127
            int c4  = (idx & 7) * 4;          // k offset within BK
            float4 fa = *(const float4*)(X + (size_t)(m0 + row) * DIM + kt + c4);
            float4 fb = *(const float4*)(muK + (size_t)(n0 + row) * DIM + kt + c4);
            short h0, h1, h2, h3, l0, l1, l2, l3;
            split_bf(fa.x, h0, l0); split_bf(fa.y, h1, l1);
            split_bf(fa.z, h2, l2); split_bf(fa.w, h3, l3);
            *(short4v*)&Ah[row * LDR + c4] = (short4v){h0, h1, h2, h3};
            *(short4v*)&Al[row * LDR + c4] = (short4v){l0, l1, l2, l3};
            split_bf(fb.x, h0, l0); split_bf(fb.y, h1, l1);
            split_bf(fb.z, h2, l2); split_bf(fb.w, h3, l3);
            *(short4v*)&Bh[row * LDR + c4] = (short4v){h0, h1, h2, h3};
            *(short4v*)&Bl[row * LDR + c4] = (short4v){l0, l1, l2, l3};
        }
        __syncthreads();
        // ---- compute: A frags [m=lane&15][k=quad*8+j] ----
        short8 ah[4], al[4];
#pragma unroll
        for (int mt = 0; mt < 4; ++mt) {
            int r = wm + mt * 16 + l16;
            ah[mt] = *(const short8*)&Ah[r * LDR + quad * 8];
            al[mt] = *(const short8*)&Al[r * LDR + quad * 8];
        }
#pragma unroll
        for (int nt = 0; nt < 4; ++nt) {
            int r = wn + nt * 16 + l16;
            short8 bh = *(const short8*)&Bh[r * LDR + quad * 8];
            short8 bl = *(const short8*)&Bl[r * LDR + quad * 8];
#pragma unroll
            for (int mt = 0; mt < 4; ++mt)
                acc[mt][nt] = __builtin_amdgcn_mfma_f32_16x16x32_bf16(ah[mt], bh, acc[mt][nt], 0, 0, 0);
#pragma unroll
            for (int mt = 0; mt < 4; ++mt)
                acc[mt][nt] = __builtin_amdgcn_mfma_f32_16x16x32_bf16(ah[mt], bl, acc[mt][nt], 0, 0, 0);
#pragma unroll
            for (int mt = 0; mt < 4; ++mt)
                acc[mt][nt] = __builtin_amdgcn_mfma_f32_16x16x32_bf16(al[mt], bh, acc[mt][nt], 0, 0, 0);
        }
    }

    // ---- epilogue: C/D layout col=lane&15, row=quad*4+reg ----
#pragma unroll
    for (int nt = 0; nt < 4; ++nt) {
        int col = n0 + wn + nt * 16 + l16;
        float mm = m2[col];
#pragma unroll
        for (int mt = 0; mt < 4; ++mt) {
            int rbase = m0 + wm + mt * 16 + quad * 4;
#pragma unroll
            for (int r = 0; r < 4; ++r)
                S[(size_t)(rbase + r) * N_CLS + col] = 2.0f * acc[mt][nt][r] - mm;
        }
    }
}

// ---------------- masked row softmax, in-place on S ----------------
__global__ __launch_bounds__(256) void softmax_kernel(float* __restrict__ S,
                                                      const float* __restrict__ cK) {
    const int row = blockIdx.x;
    float* p = S + (size_t)row * N_CLS;
    const int t = threadIdx.x;

    float v[8];
    bool  msk[8];
    float mn = FLT_MAX, mx = -FLT_MAX;
#pragma unroll
    for (int i = 0; i < 8; ++i) {
        int c = t + 256 * i;
        float s = p[c];
        v[i] = s;
        bool m = (cK[c] == 0.0f);
        msk[i] = m;
        mn = fminf(mn, s);            // min over ALL columns (pre-mask, per reference)
        if (!m) mx = fmaxf(mx, s);    // max over surviving columns
    }
    for (int off = 32; off; off >>= 1) {
        mn = fminf(mn, __shfl_xor(mn, off));
        mx = fmaxf(mx, __shfl_xor(mx, off));
    }
    __shared__ float smn[4], smx[4], ssum[4];
    const int wid = t >> 6;
    if ((t & 63) == 0) { smn[wid] = mn; smx[wid] = mx; }
    __syncthreads();
    mn = fminf(fminf(smn[0], smn[1]), fminf(smn[2], smn[3]));
    mx = fmaxf(fmaxf(smx[0], smx[1]), fmaxf(smx[2], smx[3]));
    if (mx == -FLT_MAX) mx = mn - 1.0f;   // all-masked guard
    const float fill = mn - 1.0f;

    float e[8];
    float sum = 0.f;
#pragma unroll
    for (int i = 0; i < 8; ++i) {
        float val = msk[i] ? fill : v[i];
        e[i] = __expf(val - mx);
        sum += e[i];
    }
    for (int off = 32; off; off >>= 1) sum += __shfl_xor(sum, off);
    if ((t & 63) == 0) ssum[wid] = sum;
    __syncthreads();
    sum = ssum[0] + ssum[1] + ssum[2] + ssum[3];
    const float inv = 1.0f / sum;
#pragma unroll
    for (int i = 0; i < 8; ++i)
        p[t + 256 * i] = e[i] * inv;
}

extern "C" void kernel_launch(void* const* d_in, const int* in_sizes, int n_in,
                              void* d_out, int out_size, void* d_ws, size_t ws_size,
                              hipStream_t stream) {
    const float* X   = (const float*)d_in[0];   // (32768, 512)
    const float* muK = (const float*)d_in[1];   // (2048, 512)
    const float* cK  = (const float*)d_in[2];   // (2048,)
    float* out = (float*)d_out;                 // (32768, 2048)
    float* m2  = (float*)d_ws;                  // 2048 floats of scratch

    m2_kernel<<<N_CLS, 256, 0, stream>>>(muK, m2);
    dim3 grid(N_CLS / 128, N_ROWS / 128);
    gemm_kernel<<<grid, 256, 0, stream>>>(X, muK, m2, out);
    softmax_kernel<<<N_ROWS, 256, 0, stream>>>(out, cK);
}

// Round 2
// 641.657 us; speedup vs baseline: 1.0202x; 1.0202x over previous
//
#include <hip/hip_runtime.h>
#include <cfloat>

// Problem constants
#define N_ROWS 32768
#define N_CLS  2048
#define DIM    512

typedef __attribute__((ext_vector_type(8))) short short8;
typedef __attribute__((ext_vector_type(4))) short short4v;
typedef __attribute__((ext_vector_type(4))) float f32x4;

__device__ __forceinline__ unsigned f2bf_bits(float x) {
    union { float f; unsigned u; } a; a.f = x;
    return (a.u + 0x7fffu + ((a.u >> 16) & 1u)) >> 16;   // RNE
}
__device__ __forceinline__ float bf_to_f(unsigned bits) {
    union { unsigned u; float f; } a; a.u = bits << 16;
    return a.f;
}
__device__ __forceinline__ void split_bf(float x, short &h, short &l) {
    unsigned hb = f2bf_bits(x);
    h = (short)hb;
    float r = x - bf_to_f(hb);          // exact residual
    l = (short)f2bf_bits(r);
}

// ---------------- pre-split fp32 -> (hi, lo) bf16 arrays ----------------
__global__ __launch_bounds__(256) void split_kernel(const float* __restrict__ src,
                                                    short* __restrict__ hi,
                                                    short* __restrict__ lo) {
    int idx = blockIdx.x * 256 + threadIdx.x;     // one float4 per thread
    float4 v = ((const float4*)src)[idx];
    short h0, h1, h2, h3, l0, l1, l2, l3;
    split_bf(v.x, h0, l0); split_bf(v.y, h1, l1);
    split_bf(v.z, h2, l2); split_bf(v.w, h3, l3);
    ((short4v*)hi)[idx] = (short4v){h0, h1, h2, h3};
    ((short4v*)lo)[idx] = (short4v){l0, l1, l2, l3};
}

// ---------------- m2[j] = sum_d muK[j,d]^2 ----------------
__global__ __launch_bounds__(256) void m2_kernel(const float* __restrict__ muK,
                                                 float* __restrict__ m2) {
    const int j = blockIdx.x;
    const int t = threadIdx.x;
    const float* r = muK + (size_t)j * DIM;
    float a = r[t], b = r[t + 256];
    float s = a * a + b * b;
    for (int off = 32; off; off >>= 1) s += __shfl_xor(s, off);
    __shared__ float sw[4];
    if ((t & 63) == 0) sw[t >> 6] = s;
    __syncthreads();
    if (t == 0) m2[j] = sw[0] + sw[1] + sw[2] + sw[3];
}

#define GLDS16(g, l) __builtin_amdgcn_global_load_lds( \
    (const __attribute__((address_space(1))) unsigned int*)(g), \
    (__attribute__((address_space(3))) unsigned int*)(l), 16, 0, 0)

// ---------------- concat-K bf16 GEMM (m97 structure) ----------------
// S[i,j] = 2 * sum_{k<1536} A'[i,k] B'[j,k] - m2[j], A'=[Xh|Xh|Xl], B'=[Mh|Ml|Mh]
__global__ __launch_bounds__(256) void gemm_kernel(const short* __restrict__ Xh,
                                                   const short* __restrict__ Xl,
                                                   const short* __restrict__ Mh,
                                                   const short* __restrict__ Ml,
                                                   const float* __restrict__ m2,
                                                   float* __restrict__ S) {
    __shared__ __align__(16) short As[128 * 32];
    __shared__ __align__(16) short Bs[128 * 32];

    const int tid  = threadIdx.x;
    const int n0   = blockIdx.x * 128;   // class tile
    const int m0   = blockIdx.y * 128;   // row tile
    const int w    = tid >> 6;
    const int lane = tid & 63;
    const int wm   = (w >> 1) * 64;
    const int wn   = (w & 1) * 64;
    const int l16  = lane & 15;
    const int quad = lane >> 4;

    // staging chunk ids (16B chunks); LDS dest = uniform base + lane*16
    const int c0 = w * 128 + lane;           // i=0 chunk
    const int c1 = c0 + 64;                  // i=1 chunk
    const size_t ga0 = (size_t)(m0 + (c0 >> 2)) * DIM + (c0 & 3) * 8;
    const size_t ga1 = (size_t)(m0 + (c1 >> 2)) * DIM + (c1 & 3) * 8;
    const size_t gb0 = (size_t)(n0 + (c0 >> 2)) * DIM + (c0 & 3) * 8;
    const size_t gb1 = (size_t)(n0 + (c1 >> 2)) * DIM + (c1 & 3) * 8;

    f32x4 acc[4][4];
#pragma unroll
    for (int mt = 0; mt < 4; ++mt)
#pragma unroll
        for (int nt = 0; nt < 4; ++nt)
            acc[mt][nt] = (f32x4){0.f, 0.f, 0.f, 0.f};

#pragma unroll 1
    for (int seg = 0; seg < 3; ++seg) {
        const short* Ap = (seg == 2) ? Xl : Xh;
        const short* Bp = (seg == 1) ? Ml : Mh;
#pragma unroll 1
        for (int kt2 = 0; kt2 < 16; ++kt2) {
            const int kk = kt2 * 32;
            __syncthreads();
            GLDS16(Ap + ga0 + kk, &As[c0 * 8]);
            GLDS16(Ap + ga1 + kk, &As[c1 * 8]);
            GLDS16(Bp + gb0 + kk, &Bs[c0 * 8]);
            GLDS16(Bp + gb1 + kk, &Bs[c1 * 8]);
            __syncthreads();

            short8 ah[4];
#pragma unroll
            for (int mt = 0; mt < 4; ++mt)
                ah[mt] = *(const short8*)&As[(wm + mt * 16 + l16) * 32 + quad * 8];
#pragma unroll
            for (int nt = 0; nt < 4; ++nt) {
                short8 bf = *(const short8*)&Bs[(wn + nt * 16 + l16) * 32 + quad * 8];
#pragma unroll
                for (int mt = 0; mt < 4; ++mt)
                    acc[mt][nt] = __builtin_amdgcn_mfma_f32_16x16x32_bf16(ah[mt], bf, acc[mt][nt], 0, 0, 0);
            }
        }
    }

    // epilogue: C/D layout col=lane&15, row=quad*4+reg
#pragma unroll
    for (int nt = 0; nt < 4; ++nt) {
        int col = n0 + wn + nt * 16 + l16;
        float mm = m2[col];
#pragma unroll
        for (int mt = 0; mt < 4; ++mt) {
            int rbase = m0 + wm + mt * 16 + quad * 4;
#pragma unroll
            for (int r = 0; r < 4; ++r)
                S[(size_t)(rbase + r) * N_CLS + col] = 2.0f * acc[mt][nt][r] - mm;
        }
    }
}

// ---------------- round-1 fallback GEMM (in-kernel split; needs no big ws) ----------------
#define LDR 40
__global__ __launch_bounds__(256) void gemm_fallback(const float* __restrict__ X,
                                                     const float* __restrict__ muK,
                                                     const float* __restrict__ m2,
                                                     float* __restrict__ S) {
    __shared__ __align__(16) short Ah[128 * LDR];
    __shared__ __align__(16) short Al[128 * LDR];
    __shared__ __align__(16) short Bh[128 * LDR];
    __shared__ __align__(16) short Bl[128 * LDR];
    const int tid  = threadIdx.x;
    const int n0   = blockIdx.x * 128;
    const int m0   = blockIdx.y * 128;
    const int w    = tid >> 6;
    const int lane = tid & 63;
    const int wm   = (w >> 1) * 64;
    const int wn   = (w & 1) * 64;
    const int l16  = lane & 15;
    const int quad = lane >> 4;
    f32x4 acc[4][4];
#pragma unroll
    for (int mt = 0; mt < 4; ++mt)
#pragma unroll
        for (int nt = 0; nt < 4; ++nt)
            acc[mt][nt] = (f32x4){0.f, 0.f, 0.f, 0.f};
    for (int kt = 0; kt < DIM; kt += 32) {
        __syncthreads();
#pragma unroll
        for (int i = 0; i < 4; ++i) {
            int idx = tid + 256 * i;
            int row = idx >> 3;
            int c4  = (idx & 7) * 4;
            float4 fa = *(const float4*)(X + (size_t)(m0 + row) * DIM + kt + c4);
            float4 fb = *(const float4*)(muK + (size_t)(n0 + row) * DIM + kt + c4);
            short h0, h1, h2, h3, l0, l1, l2, l3;
            split_bf(fa.x, h0, l0); split_bf(fa.y, h1, l1);
            split_bf(fa.z, h2, l2); split_bf(fa.w, h3, l3);
            *(short4v*)&Ah[row * LDR + c4] = (short4v){h0, h1, h2, h3};
            *(short4v*)&Al[row * LDR + c4] = (short4v){l0, l1, l2, l3};
            split_bf(fb.x, h0, l0); split_bf(fb.y, h1, l1);
            split_bf(fb.z, h2, l2); split_bf(fb.w, h3, l3);
            *(short4v*)&Bh[row * LDR + c4] = (short4v){h0, h1, h2, h3};
            *(short4v*)&Bl[row * LDR + c4] = (short4v){l0, l1, l2, l3};
        }
        __syncthreads();
        short8 ah[4], al[4];
#pragma unroll
        for (int mt = 0; mt < 4; ++mt) {
            int r = wm + mt * 16 + l16;
            ah[mt] = *(const short8*)&Ah[r * LDR + quad * 8];
            al[mt] = *(const short8*)&Al[r * LDR + quad * 8];
        }
#pragma unroll
        for (int nt = 0; nt < 4; ++nt) {
            int r = wn + nt * 16 + l16;
            short8 bh = *(const short8*)&Bh[r * LDR + quad * 8];
            short8 bl = *(const short8*)&Bl[r * LDR + quad * 8];
#pragma unroll
            for (int mt = 0; mt < 4; ++mt)
                acc[mt][nt] = __builtin_amdgcn_mfma_f32_16x16x32_bf16(ah[mt], bh, acc[mt][nt], 0, 0, 0);
#pragma unroll
            for (int mt = 0; mt < 4; ++mt)
                acc[mt][nt] = __builtin_amdgcn_mfma_f32_16x16x32_bf16(ah[mt], bl, acc[mt][nt], 0, 0, 0);
#pragma unroll
            for (int mt = 0; mt < 4; ++mt)
                acc[mt][nt] = __builtin_amdgcn_mfma_f32_16x16x32_bf16(al[mt], bh, acc[mt][nt], 0, 0, 0);
        }
    }
#pragma unroll
    for (int nt = 0; nt < 4; ++nt) {
        int col = n0 + wn + nt * 16 + l16;
        float mm = m2[col];
#pragma unroll
        for (int mt = 0; mt < 4; ++mt) {
            int rbase = m0 + wm + mt * 16 + quad * 4;
#pragma unroll
            for (int r = 0; r < 4; ++r)
                S[(size_t)(rbase + r) * N_CLS + col] = 2.0f * acc[mt][nt][r] - mm;
        }
    }
}

// ---------------- masked row softmax, wave-per-row, in-place ----------------
__global__ __launch_bounds__(256) void softmax_kernel(float* __restrict__ S,
                                                      const float* __restrict__ cK) {
    const int row  = blockIdx.x * 4 + (threadIdx.x >> 6);
    const int lane = threadIdx.x & 63;
    float4* p = (float4*)(S + (size_t)row * N_CLS);
    const float4* ck4 = (const float4*)cK;

    float4 v[8];
    unsigned msk = 0;
    float mn = FLT_MAX, mx = -FLT_MAX;
#pragma unroll
    for (int i = 0; i < 8; ++i) {
        int c = i * 64 + lane;
        float4 s = p[c];
        float4 k = ck4[c];
        v[i] = s;
        if (k.x == 0.f) msk |= 1u << (i * 4 + 0); else mx = fmaxf(mx, s.x);
        if (k.y == 0.f) msk |= 1u << (i * 4 + 1); else mx = fmaxf(mx, s.y);
        if (k.z == 0.f) msk |= 1u << (i * 4 + 2); else mx = fmaxf(mx, s.z);
        if (k.w == 0.f) msk |= 1u << (i * 4 + 3); else mx = fmaxf(mx, s.w);
        mn = fminf(mn, fminf(fminf(s.x, s.y), fminf(s.z, s.w)));
    }
    for (int off = 32; off; off >>= 1) {
        mn = fminf(mn, __shfl_xor(mn, off));
        mx = fmaxf(mx, __shfl_xor(mx, off));
    }
    if (mx == -FLT_MAX) mx = mn - 1.0f;
    const float fill = mn - 1.0f;

    float sum = 0.f;
#pragma unroll
    for (int i = 0; i < 8; ++i) {
        float4 s = v[i];
        s.x = __expf(((msk >> (i * 4 + 0)) & 1u ? fill : s.x) - mx);
        s.y = __expf(((msk >> (i * 4 + 1)) & 1u ? fill : s.y) - mx);
        s.z = __expf(((msk >> (i * 4 + 2)) & 1u ? fill : s.z) - mx);
        s.w = __expf(((msk >> (i * 4 + 3)) & 1u ? fill : s.w) - mx);
        sum += s.x + s.y + s.z + s.w;
        v[i] = s;
    }
    for (int off = 32; off; off >>= 1) sum += __shfl_xor(sum, off);
    const float inv = 1.0f / sum;
#pragma unroll
    for (int i = 0; i < 8; ++i) {
        float4 s = v[i];
        s.x *= inv; s.y *= inv; s.z *= inv; s.w *= inv;
        p[i * 64 + lane] = s;
    }
}

extern "C" void kernel_launch(void* const* d_in, const int* in_sizes, int n_in,
                              void* d_out, int out_size, void* d_ws, size_t ws_size,
                              hipStream_t stream) {
    const float* X   = (const float*)d_in[0];   // (32768, 512)
    const float* muK = (const float*)d_in[1];   // (2048, 512)
    const float* cK  = (const float*)d_in[2];   // (2048,)
    float* out = (float*)d_out;                 // (32768, 2048)

    // ws layout: Xh 32MB | Xl 32MB | Mh 2MB | Ml 2MB | m2 8KB
    const size_t XN = (size_t)N_ROWS * DIM;     // 16M elems
    const size_t MN = (size_t)N_CLS * DIM;      // 1M elems
    short* Xh = (short*)d_ws;
    short* Xl = Xh + XN;
    short* Mh = Xl + XN;
    short* Ml = Mh + MN;
    float* m2 = (float*)(Ml + MN);
    const size_t need = (2 * XN + 2 * MN) * sizeof(short) + N_CLS * sizeof(float);

    if (ws_size >= need) {
        split_kernel<<<(int)(XN / 4 / 256), 256, 0, stream>>>(X, Xh, Xl);
        split_kernel<<<(int)(MN / 4 / 256), 256, 0, stream>>>(muK, Mh, Ml);
        m2_kernel<<<N_CLS, 256, 0, stream>>>(muK, m2);
        dim3 grid(N_CLS / 128, N_ROWS / 128);
        gemm_kernel<<<grid, 256, 0, stream>>>(Xh, Xl, Mh, Ml, m2, out);
    } else {
        float* m2f = (float*)d_ws;
        m2_kernel<<<N_CLS, 256, 0, stream>>>(muK, m2f);
        dim3 grid(N_CLS / 128, N_ROWS / 128);
        gemm_fallback<<<grid, 256, 0, stream>>>(X, muK, m2f, out);
    }
    softmax_kernel<<<N_ROWS / 4, 256, 0, stream>>>(out, cK);
}

// Round 4
// 620.718 us; speedup vs baseline: 1.0546x; 1.0337x over previous
//
#include <hip/hip_runtime.h>
#include <cfloat>

// Problem constants
#define N_ROWS 32768
#define N_CLS  2048
#define DIM    512

typedef __attribute__((ext_vector_type(8))) short short8;
typedef __attribute__((ext_vector_type(4))) short short4v;
typedef __attribute__((ext_vector_type(4))) float f32x4;

__device__ __forceinline__ unsigned f2bf_bits(float x) {
    union { float f; unsigned u; } a; a.f = x;
    return (a.u + 0x7fffu + ((a.u >> 16) & 1u)) >> 16;   // RNE
}
__device__ __forceinline__ float bf_to_f(unsigned bits) {
    union { unsigned u; float f; } a; a.u = bits << 16;
    return a.f;
}
__device__ __forceinline__ void split_bf(float x, short &h, short &l) {
    unsigned hb = f2bf_bits(x);
    h = (short)hb;
    float r = x - bf_to_f(hb);          // exact residual
    l = (short)f2bf_bits(r);
}

// ---------------- pre-split fp32 -> (hi, lo) bf16 arrays ----------------
__global__ __launch_bounds__(256) void split_kernel(const float* __restrict__ src,
                                                    short* __restrict__ hi,
                                                    short* __restrict__ lo) {
    int idx = blockIdx.x * 256 + threadIdx.x;     // one float4 per thread
    float4 v = ((const float4*)src)[idx];
    short h0, h1, h2, h3, l0, l1, l2, l3;
    split_bf(v.x, h0, l0); split_bf(v.y, h1, l1);
    split_bf(v.z, h2, l2); split_bf(v.w, h3, l3);
    ((short4v*)hi)[idx] = (short4v){h0, h1, h2, h3};
    ((short4v*)lo)[idx] = (short4v){l0, l1, l2, l3};
}

// ---------------- m2[j] = sum_d muK[j,d]^2 ----------------
__global__ __launch_bounds__(256) void m2_kernel(const float* __restrict__ muK,
                                                 float* __restrict__ m2) {
    const int j = blockIdx.x;
    const int t = threadIdx.x;
    const float* r = muK + (size_t)j * DIM;
    float a = r[t], b = r[t + 256];
    float s = a * a + b * b;
    for (int off = 32; off; off >>= 1) s += __shfl_xor(s, off);
    __shared__ float sw[4];
    if ((t & 63) == 0) sw[t >> 6] = s;
    __syncthreads();
    if (t == 0) m2[j] = sw[0] + sw[1] + sw[2] + sw[3];
}

#define GLDS16(g, l) __builtin_amdgcn_global_load_lds( \
    (const __attribute__((address_space(1))) unsigned int*)(g), \
    (__attribute__((address_space(3))) unsigned int*)(l), 16, 0, 0)

// ---------------- concat-K bf16 GEMM (m97 structure) ----------------
// S[i,j] = 2 * sum_{k<1536} A'[i,k] B'[j,k] - m2[j], A'=[Xh|Xh|Xl], B'=[Mh|Ml|Mh]
__global__ __launch_bounds__(256) void gemm_kernel(const short* __restrict__ Xh,
                                                   const short* __restrict__ Xl,
                                                   const short* __restrict__ Mh,
                                                   const short* __restrict__ Ml,
                                                   const float* __restrict__ m2,
                                                   float* __restrict__ S) {
    __shared__ __align__(16) short As[128 * 32];
    __shared__ __align__(16) short Bs[128 * 32];

    const int tid  = threadIdx.x;
    const int n0   = blockIdx.x * 128;   // class tile
    const int m0   = blockIdx.y * 128;   // row tile
    const int w    = tid >> 6;
    const int lane = tid & 63;
    const int wm   = (w >> 1) * 64;
    const int wn   = (w & 1) * 64;
    const int l16  = lane & 15;
    const int quad = lane >> 4;

    // staging chunk ids (16B chunks); LDS dest = uniform base + lane*16
    const int c0 = w * 128 + lane;           // i=0 chunk
    const int c1 = c0 + 64;                  // i=1 chunk
    const size_t ga0 = (size_t)(m0 + (c0 >> 2)) * DIM + (c0 & 3) * 8;
    const size_t ga1 = (size_t)(m0 + (c1 >> 2)) * DIM + (c1 & 3) * 8;
    const size_t gb0 = (size_t)(n0 + (c0 >> 2)) * DIM + (c0 & 3) * 8;
    const size_t gb1 = (size_t)(n0 + (c1 >> 2)) * DIM + (c1 & 3) * 8;

    f32x4 acc[4][4];
#pragma unroll
    for (int mt = 0; mt < 4; ++mt)
#pragma unroll
        for (int nt = 0; nt < 4; ++nt)
            acc[mt][nt] = (f32x4){0.f, 0.f, 0.f, 0.f};

#pragma unroll 1
    for (int seg = 0; seg < 3; ++seg) {
        const short* Ap = (seg == 2) ? Xl : Xh;
        const short* Bp = (seg == 1) ? Ml : Mh;
#pragma unroll 1
        for (int kt2 = 0; kt2 < 16; ++kt2) {
            const int kk = kt2 * 32;
            __syncthreads();
            GLDS16(Ap + ga0 + kk, &As[c0 * 8]);
            GLDS16(Ap + ga1 + kk, &As[c1 * 8]);
            GLDS16(Bp + gb0 + kk, &Bs[c0 * 8]);
            GLDS16(Bp + gb1 + kk, &Bs[c1 * 8]);
            __syncthreads();

            short8 ah[4];
#pragma unroll
            for (int mt = 0; mt < 4; ++mt)
                ah[mt] = *(const short8*)&As[(wm + mt * 16 + l16) * 32 + quad * 8];
#pragma unroll
            for (int nt = 0; nt < 4; ++nt) {
                short8 bf = *(const short8*)&Bs[(wn + nt * 16 + l16) * 32 + quad * 8];
#pragma unroll
                for (int mt = 0; mt < 4; ++mt)
                    acc[mt][nt] = __builtin_amdgcn_mfma_f32_16x16x32_bf16(ah[mt], bf, acc[mt][nt], 0, 0, 0);
            }
        }
    }

    // epilogue: C/D layout col=lane&15, row=quad*4+reg
#pragma unroll
    for (int nt = 0; nt < 4; ++nt) {
        int col = n0 + wn + nt * 16 + l16;
        float mm = m2[col];
#pragma unroll
        for (int mt = 0; mt < 4; ++mt) {
            int rbase = m0 + wm + mt * 16 + quad * 4;
#pragma unroll
            for (int r = 0; r < 4; ++r)
                S[(size_t)(rbase + r) * N_CLS + col] = 2.0f * acc[mt][nt][r] - mm;
        }
    }
}

// ---------------- round-1 fallback GEMM (in-kernel split; needs no big ws) ----------------
#define LDR 40
__global__ __launch_bounds__(256) void gemm_fallback(const float* __restrict__ X,
                                                     const float* __restrict__ muK,
                                                     const float* __restrict__ m2,
                                                     float* __restrict__ S) {
    __shared__ __align__(16) short Ah[128 * LDR];
    __shared__ __align__(16) short Al[128 * LDR];
    __shared__ __align__(16) short Bh[128 * LDR];
    __shared__ __align__(16) short Bl[128 * LDR];
    const int tid  = threadIdx.x;
    const int n0   = blockIdx.x * 128;
    const int m0   = blockIdx.y * 128;
    const int w    = tid >> 6;
    const int lane = tid & 63;
    const int wm   = (w >> 1) * 64;
    const int wn   = (w & 1) * 64;
    const int l16  = lane & 15;
    const int quad = lane >> 4;
    f32x4 acc[4][4];
#pragma unroll
    for (int mt = 0; mt < 4; ++mt)
#pragma unroll
        for (int nt = 0; nt < 4; ++nt)
            acc[mt][nt] = (f32x4){0.f, 0.f, 0.f, 0.f};
    for (int kt = 0; kt < DIM; kt += 32) {
        __syncthreads();
#pragma unroll
        for (int i = 0; i < 4; ++i) {
            int idx = tid + 256 * i;
            int row = idx >> 3;
            int c4  = (idx & 7) * 4;
            float4 fa = *(const float4*)(X + (size_t)(m0 + row) * DIM + kt + c4);
            float4 fb = *(const float4*)(muK + (size_t)(n0 + row) * DIM + kt + c4);
            short h0, h1, h2, h3, l0, l1, l2, l3;
            split_bf(fa.x, h0, l0); split_bf(fa.y, h1, l1);
            split_bf(fa.z, h2, l2); split_bf(fa.w, h3, l3);
            *(short4v*)&Ah[row * LDR + c4] = (short4v){h0, h1, h2, h3};
            *(short4v*)&Al[row * LDR + c4] = (short4v){l0, l1, l2, l3};
            split_bf(fb.x, h0, l0); split_bf(fb.y, h1, l1);
            split_bf(fb.z, h2, l2); split_bf(fb.w, h3, l3);
            *(short4v*)&Bh[row * LDR + c4] = (short4v){h0, h1, h2, h3};
            *(short4v*)&Bl[row * LDR + c4] = (short4v){l0, l1, l2, l3};
        }
        __syncthreads();
        short8 ah[4], al[4];
#pragma unroll
        for (int mt = 0; mt < 4; ++mt) {
            int r = wm + mt * 16 + l16;
            ah[mt] = *(const short8*)&Ah[r * LDR + quad * 8];
            al[mt] = *(const short8*)&Al[r * LDR + quad * 8];
        }
#pragma unroll
        for (int nt = 0; nt < 4; ++nt) {
            int r = wn + nt * 16 + l16;
            short8 bh = *(const short8*)&Bh[r * LDR + quad * 8];
            short8 bl = *(const short8*)&Bl[r * LDR + quad * 8];
#pragma unroll
            for (int mt = 0; mt < 4; ++mt)
                acc[mt][nt] = __builtin_amdgcn_mfma_f32_16x16x32_bf16(ah[mt], bh, acc[mt][nt], 0, 0, 0);
#pragma unroll
            for (int mt = 0; mt < 4; ++mt)
                acc[mt][nt] = __builtin_amdgcn_mfma_f32_16x16x32_bf16(ah[mt], bl, acc[mt][nt], 0, 0, 0);
#pragma unroll
            for (int mt = 0; mt < 4; ++mt)
                acc[mt][nt] = __builtin_amdgcn_mfma_f32_16x16x32_bf16(al[mt], bh, acc[mt][nt], 0, 0, 0);
        }
    }
#pragma unroll
    for (int nt = 0; nt < 4; ++nt) {
        int col = n0 + wn + nt * 16 + l16;
        float mm = m2[col];
#pragma unroll
        for (int mt = 0; mt < 4; ++mt) {
            int rbase = m0 + wm + mt * 16 + quad * 4;
#pragma unroll
            for (int r = 0; r < 4; ++r)
                S[(size_t)(rbase + r) * N_CLS + col] = 2.0f * acc[mt][nt][r] - mm;
        }
    }
}

// ---------------- masked row softmax, wave-per-row, in-place, nontemporal ----------------
__global__ __launch_bounds__(256) void softmax_kernel(float* __restrict__ S,
                                                      const float* __restrict__ cK) {
    const int row  = blockIdx.x * 4 + (threadIdx.x >> 6);
    const int lane = threadIdx.x & 63;
    f32x4* p = (f32x4*)(S + (size_t)row * N_CLS);
    const float4* ck4 = (const float4*)cK;

    f32x4 v[8];
    unsigned msk = 0;
    float mn = FLT_MAX, mx = -FLT_MAX;
#pragma unroll
    for (int i = 0; i < 8; ++i) {
        int c = i * 64 + lane;
        f32x4 s = __builtin_nontemporal_load(&p[c]);    // streamed: no L2 allocation
        float4 k = ck4[c];                              // hot 8 KB: keep cached
        v[i] = s;
        if (k.x == 0.f) msk |= 1u << (i * 4 + 0); else mx = fmaxf(mx, s.x);
        if (k.y == 0.f) msk |= 1u << (i * 4 + 1); else mx = fmaxf(mx, s.y);
        if (k.z == 0.f) msk |= 1u << (i * 4 + 2); else mx = fmaxf(mx, s.z);
        if (k.w == 0.f) msk |= 1u << (i * 4 + 3); else mx = fmaxf(mx, s.w);
        mn = fminf(mn, fminf(fminf(s.x, s.y), fminf(s.z, s.w)));
    }
    for (int off = 32; off; off >>= 1) {
        mn = fminf(mn, __shfl_xor(mn, off));
        mx = fmaxf(mx, __shfl_xor(mx, off));
    }
    if (mx == -FLT_MAX) mx = mn - 1.0f;
    const float fill = mn - 1.0f;

    float sum = 0.f;
#pragma unroll
    for (int i = 0; i < 8; ++i) {
        f32x4 s = v[i];
        s.x = __expf(((msk >> (i * 4 + 0)) & 1u ? fill : s.x) - mx);
        s.y = __expf(((msk >> (i * 4 + 1)) & 1u ? fill : s.y) - mx);
        s.z = __expf(((msk >> (i * 4 + 2)) & 1u ? fill : s.z) - mx);
        s.w = __expf(((msk >> (i * 4 + 3)) & 1u ? fill : s.w) - mx);
        sum += s.x + s.y + s.z + s.w;
        v[i] = s;
    }
    for (int off = 32; off; off >>= 1) sum += __shfl_xor(sum, off);
    const float inv = 1.0f / sum;
#pragma unroll
    for (int i = 0; i < 8; ++i) {
        f32x4 s = v[i] * inv;
        __builtin_nontemporal_store(s, &p[i * 64 + lane]);  // no write-allocate
    }
}

extern "C" void kernel_launch(void* const* d_in, const int* in_sizes, int n_in,
                              void* d_out, int out_size, void* d_ws, size_t ws_size,
                              hipStream_t stream) {
    const float* X   = (const float*)d_in[0];   // (32768, 512)
    const float* muK = (const float*)d_in[1];   // (2048, 512)
    const float* cK  = (const float*)d_in[2];   // (2048,)
    float* out = (float*)d_out;                 // (32768, 2048)

    // ws layout: Xh 32MB | Xl 32MB | Mh 2MB | Ml 2MB | m2 8KB
    const size_t XN = (size_t)N_ROWS * DIM;     // 16M elems
    const size_t MN = (size_t)N_CLS * DIM;      // 1M elems
    short* Xh = (short*)d_ws;
    short* Xl = Xh + XN;
    short* Mh = Xl + XN;
    short* Ml = Mh + MN;
    float* m2 = (float*)(Ml + MN);
    const size_t need = (2 * XN + 2 * MN) * sizeof(short) + N_CLS * sizeof(float);

    if (ws_size >= need) {
        split_kernel<<<(int)(XN / 4 / 256), 256, 0, stream>>>(X, Xh, Xl);
        split_kernel<<<(int)(MN / 4 / 256), 256, 0, stream>>>(muK, Mh, Ml);
        m2_kernel<<<N_CLS, 256, 0, stream>>>(muK, m2);
        dim3 grid(N_CLS / 128, N_ROWS / 128);
        gemm_kernel<<<grid, 256, 0, stream>>>(Xh, Xl, Mh, Ml, m2, out);
    } else {
        float* m2f = (float*)d_ws;
        m2_kernel<<<N_CLS, 256, 0, stream>>>(muK, m2f);
        dim3 grid(N_CLS / 128, N_ROWS / 128);
        gemm_fallback<<<grid, 256, 0, stream>>>(X, muK, m2f, out);
    }
    softmax_kernel<<<N_ROWS / 4, 256, 0, stream>>>(out, cK);
}